// Round 6
// baseline (512.456 us; speedup 1.0000x reference)
//
#include <hip/hip_runtime.h>
#include <cstdint>
#include <cstddef>

// DenseCaps dynamic routing, MI355X. B=256, R=2048, NC=10, OUT=16, IN=8, 3 iters.
//
// R6: recompute-u structure (no materialized u_hat), fixing R5's measured
// sins: (1) 1.3M device atomics -> 146MB WRITE_SIZE + fabric serialization;
// (2) btile=4 quadrupled W L2 traffic; (3) scalar-only FMA.
//  - NO atomics: blocks write private partials to a 10.5MB slab (coalesced);
//    a tiny reduce kernel sums 64 partials per (b,n,o), computes v=squash(s)
//    and maintains the running vsum (deferred-logit form, verified R2-R5).
//    No memsets needed at all.
//  - wave = route: lane = (bslot 0..3, class n 0..15). W[r] fetched once per
//    wave per route (10x16B per instr); btile 8 = 2 bi x 4 bslot -> W L2
//    traffic halved vs R5; acc stays in registers (f32x2[2][8]).
//  - v_pk_fma_f32 (inline asm) for u-FMA / dot / acc: 2 fp32 FMA per inst,
//    bitwise-identical per-half to scalar fmaf.
//  - XCD locality: blockIdx = bgrp*64 + rc, XCD = rc%8 -> blocks sharing a
//    W panel share an L2 (~1.3MB W per XCD).

#define B_   256
#define R_   2048
#define NC_  10
#define NR_  8          // r-steps per block (4 routes/step via 4 waves)
#define BT_  8          // b-tile per block (2 bi x 4 bslot)

typedef __attribute__((ext_vector_type(2))) float f32x2;
typedef __attribute__((ext_vector_type(4))) float f32x4;

__device__ __forceinline__ f32x2 pk_fma(f32x2 a, f32x2 b, f32x2 c){
  f32x2 d;
  asm("v_pk_fma_f32 %0, %1, %2, %3" : "=v"(d) : "v"(a), "v"(b), "v"(c));
  return d;
}
__device__ __forceinline__ float rsum16(float x){
  x += __shfl_xor(x, 1, 16);
  x += __shfl_xor(x, 2, 16);
  x += __shfl_xor(x, 4, 16);
  x += __shfl_xor(x, 8, 16);
  return x;
}
__device__ __forceinline__ float rmax16(float x){
  x = fmaxf(x, __shfl_xor(x, 1, 16));
  x = fmaxf(x, __shfl_xor(x, 2, 16));
  x = fmaxf(x, __shfl_xor(x, 4, 16));
  x = fmaxf(x, __shfl_xor(x, 8, 16));
  return x;
}

// MODE 0: c = softmax(b_in)                    -> slab partial of s0
// MODE k: c = softmax(b_in + dot(u, vsum_{k-1})) -> slab partial of s_k
// MODE 3 additionally writes c to c_out.
template<int MODE>
__global__ __launch_bounds__(256, 2) void route_pass(
    const float* __restrict__ x,     // [256][2048][8]
    const float* __restrict__ W,     // [2048][8][160]
    const float* __restrict__ b_in,  // [2048][10]
    float*       __restrict__ c_out, // [256][2048][10]
    const float* __restrict__ vsum,  // [256][160]  (v0+..+v_{MODE-1})
    float*       __restrict__ slab)  // [2048 blocks][8 b][160]
{
  const int t     = threadIdx.x;
  const int rc    = blockIdx.x & 63;   // r-chunk; XCD = rc%8
  const int bgrp  = blockIdx.x >> 6;   // 0..31
  const int b0    = bgrp * BT_;
  const int r0    = rc * (4 * NR_);
  const int w     = t >> 6;            // wave id = route-within-step
  const int lane  = t & 63;
  const int bslot = lane >> 4;         // 0..3
  const int n     = lane & 15;         // class lane (10 active)
  const int nn    = (n < NC_) ? n : (NC_ - 1);

  __shared__ float xs[BT_ * 32 * 8];   // 8 KB   [b][rl][i]
  __shared__ float vs[BT_ * 180];      // 5.8 KB [b][n*18+o] (stride 18: spread banks)
  __shared__ float fl[4 * BT_ * 176];  // 22.5 KB [w][b][n*17+o]

  // ---- stage x tile: 2048 floats = 512 uint4, coalesced (1KB runs per b)
  for (int idx = t; idx < 512; idx += 256){
    int bb = idx >> 6, inner = idx & 63;
    ((uint4*)xs)[bb * 64 + inner] =
      *(const uint4*)(x + ((size_t)(b0 + bb) * R_ + r0) * 8 + inner * 4);
  }
  // ---- stage vsum for the block's 8 b's (contiguous 5KB read)
  if (MODE >= 1){
    for (int idx = t; idx < BT_ * 160; idx += 256){
      int bb = idx / 160, rem = idx - bb * 160;
      int nr = rem >> 4, oo = rem & 15;
      vs[bb * 180 + nr * 18 + oo] = vsum[(size_t)(b0 + bb) * 160 + rem];
    }
  }
  __syncthreads();

  f32x2 acc[2][8];
  #pragma unroll
  for (int bi = 0; bi < 2; ++bi)
    #pragma unroll
    for (int o2 = 0; o2 < 8; ++o2) acc[bi][o2] = f32x2{0.f, 0.f};

  for (int step = 0; step < NR_; ++step){
    const int r = r0 + step * 4 + w;
    // W[r] fragment for this lane's class: 32 dwordx4 (wave reads row once)
    f32x4 w4[32];
    {
      const float* wp = W + (size_t)r * 1280 + nn * 16;
      #pragma unroll
      for (int i = 0; i < 8; ++i)
        #pragma unroll
        for (int q = 0; q < 4; ++q)
          w4[i * 4 + q] = *(const f32x4*)(wp + i * 160 + q * 4);
    }
    const f32x2* w2 = (const f32x2*)w4;
    const float binr = b_in[r * NC_ + nn];
    float c0r = 0.f;
    if (MODE == 0){
      float bnew = (n < NC_) ? binr : -1e30f;
      float m = rmax16(bnew);
      float e = __expf(bnew - m);
      float sum = rsum16(e);
      c0r = e / sum;
    }

    #pragma unroll
    for (int bi = 0; bi < 2; ++bi){
      const int bloc = bi * 4 + bslot;
      const float* xp = xs + (bloc * 32 + step * 4 + w) * 8;
      f32x4 xa = *(const f32x4*)xp;
      f32x4 xb = *(const f32x4*)(xp + 4);
      float xr[8] = {xa[0], xa[1], xa[2], xa[3], xb[0], xb[1], xb[2], xb[3]};

      f32x2 u2[8];
      #pragma unroll
      for (int o2 = 0; o2 < 8; ++o2) u2[o2] = f32x2{0.f, 0.f};
      #pragma unroll
      for (int i = 0; i < 8; ++i){
        f32x2 xi2 = {xr[i], xr[i]};
        #pragma unroll
        for (int o2 = 0; o2 < 8; ++o2)
          u2[o2] = pk_fma(w2[i * 8 + o2], xi2, u2[o2]);
      }

      float c;
      if (MODE == 0){
        c = c0r;
      } else {
        const f32x2* vrow = (const f32x2*)(vs + bloc * 180 + nn * 18);
        f32x2 t2 = {0.f, 0.f};
        #pragma unroll
        for (int o2 = 0; o2 < 8; ++o2) t2 = pk_fma(u2[o2], vrow[o2], t2);
        float td = t2[0] + t2[1];
        float bnew = (n < NC_) ? (binr + td) : -1e30f;
        float m = rmax16(bnew);
        float e = __expf(bnew - m);          // idle lanes -> 0
        float sum = rsum16(e);
        c = e / sum;
        if (MODE == 3 && n < NC_)
          c_out[((size_t)(b0 + bloc) * R_ + r) * NC_ + n] = c;
      }
      f32x2 c2 = {c, c};
      #pragma unroll
      for (int o2 = 0; o2 < 8; ++o2)
        acc[bi][o2] = pk_fma(c2, u2[o2], acc[bi][o2]);
    }
  }

  // ---- flush: per-wave copies into padded LDS, merge, one coalesced store
  if (n < NC_){
    #pragma unroll
    for (int bi = 0; bi < 2; ++bi){
      float* dst = &fl[(w * BT_ + bi * 4 + bslot) * 176 + n * 17];
      #pragma unroll
      for (int o2 = 0; o2 < 8; ++o2){
        dst[2 * o2]     = acc[bi][o2][0];
        dst[2 * o2 + 1] = acc[bi][o2][1];
      }
    }
  }
  __syncthreads();
  for (int idx = t; idx < BT_ * 160; idx += 256){
    int bb = idx / 160, rem = idx - bb * 160;
    int nr = rem >> 4, oo = rem & 15;
    float tot = 0.f;
    #pragma unroll
    for (int ww = 0; ww < 4; ++ww)
      tot += fl[(ww * BT_ + bb) * 176 + nr * 17 + oo];
    slab[(size_t)blockIdx.x * (BT_ * 160) + idx] = tot;
  }
}

// ---------- reduce: s = sum of 64 r-chunk partials; v = squash(s);
// K<3: vsum (running sum of v); K==3: write v_out. One block per b.
__global__ __launch_bounds__(256) void reduce_k(const float* __restrict__ slab,
                                                float* __restrict__ vsum,
                                                float* __restrict__ vout,
                                                int K){
  const int b = blockIdx.x;
  const int t = threadIdx.x;
  if (t >= 160) return;
  const float* p = slab + (size_t)((b >> 3) * 64) * (BT_ * 160) + (b & 7) * 160 + t;
  float s = 0.f;
  #pragma unroll 8
  for (int rcc = 0; rcc < 64; ++rcc) s += p[(size_t)rcc * (BT_ * 160)];
  float ss = rsum16(s * s);
  float v = (sqrtf(ss) / (1.f + ss + 1e-8f)) * s;
  if (K == 0)      vsum[b * 160 + t]  = v;
  else if (K < 3)  vsum[b * 160 + t] += v;
  else             vout[b * 160 + t]  = v;
}

extern "C" void kernel_launch(void* const* d_in, const int* in_sizes, int n_in,
                              void* d_out, int out_size, void* d_ws, size_t ws_size,
                              hipStream_t stream){
  const float* x    = (const float*)d_in[0];   // [256,2048,8]
  const float* W    = (const float*)d_in[1];   // [2048,8,160]
  const float* b_in = (const float*)d_in[2];   // [2048,10]
  float* out = (float*)d_out;
  float* out_v = out;                 // 40960 floats
  float* c_out = out + 40960;         // [B][R][NC] final coupling coeffs

  float* slab = (float*)d_ws;                        // 2048*1280*4 = 10.49 MB
  float* vsum = slab + (size_t)2048 * (BT_ * 160);   // 160 KB

  route_pass<0><<<2048, 256, 0, stream>>>(x, W, b_in, c_out, vsum, slab);
  reduce_k<<<256, 256, 0, stream>>>(slab, vsum, out_v, 0);
  route_pass<1><<<2048, 256, 0, stream>>>(x, W, b_in, c_out, vsum, slab);
  reduce_k<<<256, 256, 0, stream>>>(slab, vsum, out_v, 1);
  route_pass<2><<<2048, 256, 0, stream>>>(x, W, b_in, c_out, vsum, slab);
  reduce_k<<<256, 256, 0, stream>>>(slab, vsum, out_v, 2);
  route_pass<3><<<2048, 256, 0, stream>>>(x, W, b_in, c_out, vsum, slab);
  reduce_k<<<256, 256, 0, stream>>>(slab, vsum, out_v, 3);
}

// Round 8
// 354.656 us; speedup vs baseline: 1.4449x; 1.4449x over previous
//
#include <hip/hip_runtime.h>
#include <cstdint>
#include <cstddef>

// DenseCaps dynamic routing, MI355X. B=256, R=2048, NC=10, OUT=16, IN=8, 3 iters.
//
// R8 = R7 + OOB fix. R7 aborted: the W-fragment load used unclamped n
// (idle class lanes n=10..15 -> base n*16 up to 248 instead of <=152),
// reading 95 floats past row r; at r=2047 that runs past the entire W
// array -> page fault. Fix: clamp with nn (idle lanes duplicate class 9's
// in-bounds fragment; their c is 0 so values are unaffected; R4-R6 did
// exactly this).
//
// Structure (R7): recompute-u, no materialized u_hat.
//  - W fragment 64 regs/lane (lane = (rhalf, oh, n)), reloaded once per
//    r-PAIR, amortized over an 8-b register tile (~16 loads / ~900 VALU).
//  - Softmax reductions on the VALU pipe via DPP (quad_perm xor1/xor2,
//    row_half_mirror, row_mirror); one shfl remains (o-half dot merge).
//  - s-partials in registers acc[8][8]; atomic-free: coalesced slab
//    stores + reduce_k (sums 64 rb partials, squash, running vsum).
//  - LDS 64KB/block (x 32KB broadcast-read, vsum 32KB swizzled 2-way max);
//    grid 512 = 64 rb x 8 bg, exactly 2 blocks/CU, XCD-bijective map.
// Deferred logits b_k = b_in + dot(u, v0+..+v_{k-1}) (verified R2/R4/R6).

#define B_   256
#define R_   2048
#define NC_  10

typedef __attribute__((ext_vector_type(4))) float f32x4;

// ---- DPP row reductions (16-lane rows; all lanes active) ----
template<int CTRL>
__device__ __forceinline__ float dpp_mov(float x){
  return __int_as_float(__builtin_amdgcn_update_dpp(
      0, __float_as_int(x), CTRL, 0xF, 0xF, true));
}
__device__ __forceinline__ float dmax16(float x){
  x = fmaxf(x, dpp_mov<0xB1>(x));    // quad_perm xor1
  x = fmaxf(x, dpp_mov<0x4E>(x));    // quad_perm xor2
  x = fmaxf(x, dpp_mov<0x141>(x));   // row_half_mirror
  x = fmaxf(x, dpp_mov<0x140>(x));   // row_mirror
  return x;
}
__device__ __forceinline__ float dsum16(float x){
  x += dpp_mov<0xB1>(x);
  x += dpp_mov<0x4E>(x);
  x += dpp_mov<0x141>(x);
  x += dpp_mov<0x140>(x);
  return x;
}
__device__ __forceinline__ float rsum16(float x){   // reduce kernel only
  x += __shfl_xor(x, 1, 16);
  x += __shfl_xor(x, 2, 16);
  x += __shfl_xor(x, 4, 16);
  x += __shfl_xor(x, 8, 16);
  return x;
}

// MODE 0: c = softmax(b_in)                      -> slab partial of s0
// MODE k: c = softmax(b_in + dot(u, vsum_{k-1})) -> slab partial of s_k
// MODE 3 additionally writes c to c_out.
// Block: 4 waves; owns 32 r x 32 b; wave w owns b-octet w.
// Lane: rhalf = lane>>5, oh = (lane>>4)&1, n = lane&15 (10 active).
template<int MODE>
__global__ __launch_bounds__(256, 2) void route_pass(
    const float* __restrict__ x,     // [256][2048][8]
    const float* __restrict__ W,     // [2048][8][160]
    const float* __restrict__ b_in,  // [2048][10]
    float*       __restrict__ c_out, // [256][2048][10]
    const float* __restrict__ vsum,  // [256][160]
    float*       __restrict__ slab)  // [64 rb][256 b][160]
{
  const int t   = threadIdx.x;
  // bijective XCD map: idx = s + 8*bg + 64*q, rb = q*8+s -> all 8 bg
  // siblings of an rb land on XCD s.
  const int idx = blockIdx.x;
  const int s_  = idx & 7;
  const int bg  = (idx >> 3) & 7;
  const int q_  = idx >> 6;
  const int rb  = q_ * 8 + s_;      // 0..63
  const int b0g = bg * 32;
  const int r0  = rb * 32;
  const int w     = t >> 6;
  const int lane  = t & 63;
  const int rhalf = lane >> 5;
  const int oh    = (lane >> 4) & 1;
  const int n     = lane & 15;
  const int nn    = (n < NC_) ? n : (NC_ - 1);
  const int bw0   = w * 8;          // wave's b-octet within block

  __shared__ float xs[32 * 32 * 8];   // 32 KB  [bl][rl][8]
  __shared__ float vsh[32 * 256];     // 32 KB  swizzled v (2 o-chunks)

  // stage x tile (coalesced 1KB runs per b-row)
  for (int i2 = t; i2 < 2048; i2 += 256){
    int bl = i2 >> 6, rest = i2 & 63;
    ((f32x4*)xs)[i2] =
      *(const f32x4*)(x + ((size_t)(b0g + bl) * R_ + r0) * 8 + rest * 4);
  }
  // stage vsum, swizzled: v[b][n][o] -> vsh[bl*256 + (o/4)*128 + (oh*16+n)*4 + o%4]
  if (MODE >= 1){
    for (int i2 = t; i2 < 32 * 160; i2 += 256){
      int bl = i2 / 160, rem = i2 - bl * 160;
      int nr = rem >> 4, o8 = rem & 15;
      int ohh = o8 >> 3, oo = o8 & 7;
      vsh[bl * 256 + (oo >> 2) * 128 + (ohh * 16 + nr) * 4 + (oo & 3)] =
          vsum[(size_t)(b0g + bl) * 160 + rem];
    }
  }
  __syncthreads();

  float acc[8][8];
  #pragma unroll
  for (int bi = 0; bi < 8; ++bi)
    #pragma unroll
    for (int o = 0; o < 8; ++o) acc[bi][o] = 0.f;

  #pragma unroll 1
  for (int rp = 0; rp < 16; ++rp){
    const int r  = r0 + rp * 2 + rhalf;
    // W fragment: 8 i x 8 o for this lane's (nn, oh) -> 64 regs.
    // CLAMPED nn (R7 bug: n gave base up to 248 -> OOB past W at r=2047).
    f32x4 w4[16];
    {
      const float* wp = W + (size_t)r * 1280 + nn * 16 + oh * 8;
      #pragma unroll
      for (int i = 0; i < 8; ++i){
        w4[i * 2]     = *(const f32x4*)(wp + i * 160);
        w4[i * 2 + 1] = *(const f32x4*)(wp + i * 160 + 4);
      }
    }
    const float binr = b_in[r * NC_ + nn];
    float c0r = 0.f;
    if (MODE == 0){
      float bnew = (n < NC_) ? binr : -1e30f;
      float m = dmax16(bnew);
      float e = __expf(bnew - m);
      float su = dsum16(e);
      c0r = e / su;
    }

    #pragma unroll
    for (int bi = 0; bi < 8; ++bi){
      const int bl = bw0 + bi;
      const f32x4* xp = (const f32x4*)(xs + (bl * 32 + rp * 2 + rhalf) * 8);
      f32x4 xa = xp[0], xb = xp[1];     // broadcast within half-wave
      float xr[8] = {xa[0], xa[1], xa[2], xa[3], xb[0], xb[1], xb[2], xb[3]};

      float u[8];
      #pragma unroll
      for (int o = 0; o < 8; ++o) u[o] = 0.f;
      #pragma unroll
      for (int i = 0; i < 8; ++i)
        #pragma unroll
        for (int o = 0; o < 8; ++o)
          u[o] = fmaf(xr[i], w4[i * 2 + (o >> 2)][o & 3], u[o]);

      float c;
      if (MODE == 0){
        c = c0r;
      } else {
        f32x4 v0 = *(const f32x4*)(vsh + bl * 256 + (oh * 16 + n) * 4);
        f32x4 v1 = *(const f32x4*)(vsh + bl * 256 + 128 + (oh * 16 + n) * 4);
        float dp = 0.f;
        #pragma unroll
        for (int j = 0; j < 4; ++j){
          dp = fmaf(u[j],     v0[j], dp);
          dp = fmaf(u[4 + j], v1[j], dp);
        }
        dp += __shfl_xor(dp, 16, 64);       // merge o-halves
        float bnew = (n < NC_) ? (binr + dp) : -1e30f;
        float m = dmax16(bnew);
        float e = __expf(bnew - m);          // idle class lanes -> 0
        float su = dsum16(e);
        c = e / su;
        if (MODE == 3 && n < NC_ && oh == 0)
          c_out[((size_t)(b0g + bl) * R_ + r) * NC_ + n] = c;
      }
      #pragma unroll
      for (int o = 0; o < 8; ++o) acc[bi][o] = fmaf(c, u[o], acc[bi][o]);
    }
  }

  // merge the two route-halves (both contribute to the same s[b])
  #pragma unroll
  for (int bi = 0; bi < 8; ++bi)
    #pragma unroll
    for (int o = 0; o < 8; ++o)
      acc[bi][o] += __shfl_xor(acc[bi][o], 32, 64);

  // flush: one dense 640B row per (rb, b); lanes (oh, n<10) cover it exactly
  if (rhalf == 0 && n < NC_){
    #pragma unroll
    for (int bi = 0; bi < 8; ++bi){
      float* dst = slab + ((size_t)rb * 256 + (b0g + bw0 + bi)) * 160
                        + n * 16 + oh * 8;
      f32x4 lo = {acc[bi][0], acc[bi][1], acc[bi][2], acc[bi][3]};
      f32x4 hi = {acc[bi][4], acc[bi][5], acc[bi][6], acc[bi][7]};
      *(f32x4*)dst = lo;
      *(f32x4*)(dst + 4) = hi;
    }
  }
}

// ---------- reduce: s = sum of 64 rb partials; v = squash(s);
// K==0: vsum = v; K<3: vsum += v; K==3: write v_out. One block per b.
__global__ __launch_bounds__(256) void reduce_k(const float* __restrict__ slab,
                                                float* __restrict__ vsum,
                                                float* __restrict__ vout,
                                                int K){
  const int b = blockIdx.x;
  const int t = threadIdx.x;
  if (t >= 160) return;
  const float* p = slab + (size_t)b * 160 + t;
  float s = 0.f;
  #pragma unroll 8
  for (int rc = 0; rc < 64; ++rc) s += p[(size_t)rc * 40960];
  float ss = rsum16(s * s);
  float v = (sqrtf(ss) / (1.f + ss + 1e-8f)) * s;
  if (K == 0)      vsum[b * 160 + t]  = v;
  else if (K < 3)  vsum[b * 160 + t] += v;
  else             vout[b * 160 + t]  = v;
}

extern "C" void kernel_launch(void* const* d_in, const int* in_sizes, int n_in,
                              void* d_out, int out_size, void* d_ws, size_t ws_size,
                              hipStream_t stream){
  const float* x    = (const float*)d_in[0];   // [256,2048,8]
  const float* W    = (const float*)d_in[1];   // [2048,8,160]
  const float* b_in = (const float*)d_in[2];   // [2048,10]
  float* out = (float*)d_out;
  float* out_v = out;                 // 40960 floats
  float* c_out = out + 40960;         // [B][R][NC] final coupling coeffs

  float* slab = (float*)d_ws;                  // 64*256*160*4 = 10.49 MB
  float* vsum = slab + (size_t)64 * 40960;     // 160 KB

  route_pass<0><<<512, 256, 0, stream>>>(x, W, b_in, c_out, vsum, slab);
  reduce_k<<<256, 256, 0, stream>>>(slab, vsum, out_v, 0);
  route_pass<1><<<512, 256, 0, stream>>>(x, W, b_in, c_out, vsum, slab);
  reduce_k<<<256, 256, 0, stream>>>(slab, vsum, out_v, 1);
  route_pass<2><<<512, 256, 0, stream>>>(x, W, b_in, c_out, vsum, slab);
  reduce_k<<<256, 256, 0, stream>>>(slab, vsum, out_v, 2);
  route_pass<3><<<512, 256, 0, stream>>>(x, W, b_in, c_out, vsum, slab);
  reduce_k<<<256, 256, 0, stream>>>(slab, vsum, out_v, 3);
}